// Round 18
// baseline (1041.551 us; speedup 1.0000x reference)
//
#include <hip/hip_runtime.h>

#define NN 100000
#define NE 1200000
#define ITERS 5
#define NTILES (NE/16)          // 75000 edge tiles
#define TPW 16                  // tiles per wave
#define NWAVES ((NTILES+TPW-1)/TPW)
#define NBLK_E ((NWAVES+3)/4)
#define NBLK_U ((NN+63)/64)
#define NBUK ((NN+511)/512)     // 196 dst-buckets
#define BINSZ 4096
#define NBLK_BIN ((NE+BINSZ-1)/BINSZ)

typedef __attribute__((ext_vector_type(8))) short short8;
typedef __attribute__((ext_vector_type(4))) short short4_t;
typedef __attribute__((ext_vector_type(4))) float floatx4;
typedef __attribute__((ext_vector_type(4))) unsigned uintx4;
typedef unsigned short ushort_t;

__device__ inline ushort_t f2bf(float f){
  unsigned u = __float_as_uint(f);
  unsigned r = (u + 0x7fffu + ((u>>16)&1u)) >> 16;
  return (ushort_t)r;
}
// HW packed f32->bf16 (RNE), 1 VALU op for 2 values (T12 recipe; no builtin)
__device__ inline unsigned cvt_pk_bf16(float a, float b){
  unsigned r;
  asm("v_cvt_pk_bf16_f32 %0, %1, %2" : "=v"(r) : "v"(a), "v"(b));
  return r;
}
__device__ inline float bf2f(ushort_t u){ return __uint_as_float(((unsigned)u)<<16); }
__device__ inline float bf2f_lo(unsigned u){ return __uint_as_float(u<<16); }
__device__ inline float bf2f_hi(unsigned u){ return __uint_as_float(u & 0xffff0000u); }

// bijective XCD-chunked swizzle (m204)
__device__ inline int xcd_swz(int orig, int nwg){
  int q = nwg >> 3, r = nwg & 7;
  int x = orig & 7, i = orig >> 3;
  return (x < r ? x*(q+1) : r*(q+1) + (x-r)*q) + i;
}

// ------------------------- prep: counting sort by dst -------------------------
__global__ void k_count(const int* __restrict__ dst, int* __restrict__ cnt){
  int base = (blockIdx.x*256 + threadIdx.x)*4;
  if (base >= NE) return;
  int4 d4 = *reinterpret_cast<const int4*>(dst + base);
  atomicAdd(&cnt[d4.x],1); atomicAdd(&cnt[d4.y],1);
  atomicAdd(&cnt[d4.z],1); atomicAdd(&cnt[d4.w],1);
}

__global__ void k_scan1(const int* __restrict__ cnt, int* __restrict__ bsum){
  __shared__ int s[256];
  int t = threadIdx.x; int i = blockIdx.x*256 + t;
  s[t] = (i < NN) ? cnt[i] : 0; __syncthreads();
  for (int off=128; off>0; off>>=1){ if (t<off) s[t]+=s[t+off]; __syncthreads(); }
  if (t==0) bsum[blockIdx.x] = s[0];
}

__global__ void k_scan2(int* bsum, int nb){
  __shared__ int s[512];
  int t = threadIdx.x;
  int v = (t<nb)? bsum[t] : 0;
  s[t]=v; __syncthreads();
  for (int off=1; off<512; off<<=1){
    int x = (t>=off)? s[t-off] : 0; __syncthreads();
    s[t]+=x; __syncthreads();
  }
  if (t<nb) bsum[t] = s[t]-v; // exclusive
}

__global__ void k_scan3(const int* __restrict__ cnt, const int* __restrict__ bsum, int* __restrict__ rowptr){
  __shared__ int s[256];
  int t=threadIdx.x; int i = blockIdx.x*256+t;
  int v = (i<NN)? cnt[i]:0;
  s[t]=v; __syncthreads();
  for (int off=1; off<256; off<<=1){
    int x = (t>=off)? s[t-off] : 0; __syncthreads();
    s[t] += x; __syncthreads();
  }
  if (i<NN) rowptr[i] = bsum[blockIdx.x] + s[t] - v;
  if (i==0) rowptr[NN] = NE;
}

// dsts[pos] = node id, reconstructed COALESCED from rowptr (sorted by dst)
__global__ void k_filldst(const int* __restrict__ rowptr, int* __restrict__ dsts){
  int n = blockIdx.x*256 + threadIdx.x;
  if (n >= NN) return;
  int a = rowptr[n], b = rowptr[n+1];
  for (int p = a; p < b; ++p) dsts[p] = n;
}

// bucket fill seeds: bucket b's region starts at rowptr[b*512]
__global__ void k_binit(const int* __restrict__ rowptr, int* __restrict__ bfill){
  int b = blockIdx.x*256 + threadIdx.x;
  if (b >= NBUK) return;
  int n = b*512; if (n > NN) n = NN;
  bfill[b] = rowptr[n];
}

// pass 1: coarse-bin edges by dst>>9, bucket-grouped writes (low line ampl.)
__global__ void k_bin(const int* __restrict__ src, const int* __restrict__ dst,
                      const float* __restrict__ ef,
                      int* __restrict__ bfill, int4* __restrict__ btmp){
  __shared__ int hist[NBUK];
  __shared__ int base[NBUK];
  int t = threadIdx.x;
  for (int i=t; i<NBUK; i+=256) hist[i]=0;
  __syncthreads();
  int e0 = blockIdx.x*BINSZ + t;
  #pragma unroll
  for (int k=0;k<BINSZ/256;k++){
    int e = e0 + k*256;
    if (e < NE) atomicAdd(&hist[dst[e]>>9], 1);
  }
  __syncthreads();
  for (int i=t; i<NBUK; i+=256){
    int c = hist[i];
    base[i] = (c>0)? atomicAdd(&bfill[i], c) : 0;
    hist[i] = 0;
  }
  __syncthreads();
  #pragma unroll
  for (int k=0;k<BINSZ/256;k++){
    int e = e0 + k*256;
    if (e < NE){
      int d = dst[e];
      int b = d>>9;
      int off = atomicAdd(&hist[b],1);
      float2 f = reinterpret_cast<const float2*>(ef)[e];
      int efp = (int)((unsigned)f2bf(f.x)|((unsigned)f2bf(f.y)<<16));
      btmp[base[b]+off] = make_int4(src[e], d, efp, 0);
    }
  }
}

// pass 2: fine scatter within one bucket (stores land in a ~50KB L2-local window)
__global__ void k_sort2(const int4* __restrict__ btmp, const int* __restrict__ rowptr,
                        int* __restrict__ fill, int2* __restrict__ edges){
  int b = blockIdx.x;
  int nlo = b*512; if (nlo > NN) nlo = NN;
  int nhi = (b+1)*512; if (nhi > NN) nhi = NN;
  int plo = rowptr[nlo], phi = rowptr[nhi];
  for (int p = plo + threadIdx.x; p < phi; p += 256){
    int4 r = btmp[p];
    int pos = atomicAdd(&fill[r.y],1);
    edges[pos] = make_int2(r.x, r.z);
  }
}

// weights -> bf16 MFMA B-fragment order (also valid as A-fragment of W^T)
__global__ void k_wprep(const float* __restrict__ W, ushort_t* __restrict__ frag, int Ksrc, int total){
  int t = blockIdx.x*256+threadIdx.x;
  if (t>=total) return;
  int j = t&7, l=(t>>3)&63, ct=(t>>9)&3, ks=t>>11;
  int k = ks*32 + ((l>>4)<<3) + j;
  int col = ct*16 + (l&15);
  float v = (k<Ksrc)? W[k*64+col] : 0.f;
  frag[t] = f2bf(v);
}

__global__ void k_init(const float* __restrict__ nf, const float* __restrict__ W, const float* __restrict__ b,
                       ushort_t* __restrict__ hA, ushort_t* __restrict__ emb){
  int t = blockIdx.x*256+threadIdx.x;
  if (t >= NN*64) return;
  int n=t>>6, c=t&63;
  float a = b[c];
  a += nf[n*3+0]*W[0*64+c];
  a += nf[n*3+1]*W[1*64+c];
  a += nf[n*3+2]*W[2*64+c];
  emb[t] = f2bf(a);
  hA[t] = f2bf(fmaxf(a,0.f));
}

// ------------------------- edge message kernel ------------------------------
// r17-proven structure; f2bf replaced with HW v_cvt_pk_bf16_f32 in the
// transpose (MFMA1->MFMA2 critical path) and the store pack.
__launch_bounds__(256)
__global__ void k_edge(const ushort_t* __restrict__ h,
                       const int2* __restrict__ edges, const int* __restrict__ dsts,
                       const ushort_t* __restrict__ w1f, const ushort_t* __restrict__ w2f,
                       const float* __restrict__ b1, const float* __restrict__ b2,
                       ushort_t* __restrict__ m_s){
  int tid = threadIdx.x;
  int wv = tid>>6, lane = tid&63;
  int lo = lane&15, hi = lane>>4;
  int wave = xcd_swz(blockIdx.x, NBLK_E)*4 + wv;
  int t0 = wave*TPW;
  if (t0 >= NTILES) return;
  int t1 = t0 + TPW; if (t1 > NTILES) t1 = NTILES;

  const short8* w1 = reinterpret_cast<const short8*>(w1f) + lane;
  const short8* w2 = reinterpret_cast<const short8*>(w2f) + lane;

  float bb1[4][4], bb2s[4][4];
  #pragma unroll
  for (int ct=0;ct<4;ct++)
    #pragma unroll
    for (int jr=0;jr<4;jr++){
      bb1[ct][jr]  = b1[ct*16 + hi*4 + jr];
      bb2s[ct][jr] = b2[ct*16 + hi*4 + jr];
    }

  // prologue: rec(t0)+dst(t0) + gathers(t0), rec(t0+1)+dst(t0+1)
  int2 recA = edges[t0*16 + lo];
  int  dvA  = dsts[t0*16 + lo];
  short8 cg0 = *reinterpret_cast<const short8*>(h + (size_t)dvA*64 + hi*8);
  short8 cg1 = *reinterpret_cast<const short8*>(h + (size_t)dvA*64 + (4+hi)*8);
  short8 cg2 = *reinterpret_cast<const short8*>(h + (size_t)recA.x*64 + hi*8);
  short8 cg3 = *reinterpret_cast<const short8*>(h + (size_t)recA.x*64 + (4+hi)*8);
  int tB = (t0+1 < t1)? t0+1 : t0;
  int2 recB = edges[tB*16 + lo];
  int  dvB  = dsts[tB*16 + lo];

  for (int t = t0; t < t1; ++t){
    // issue gathers for t+1 NOW (consumed next iteration -> full-body cover)
    short8 ng0 = *reinterpret_cast<const short8*>(h + (size_t)dvB*64 + hi*8);
    short8 ng1 = *reinterpret_cast<const short8*>(h + (size_t)dvB*64 + (4+hi)*8);
    short8 ng2 = *reinterpret_cast<const short8*>(h + (size_t)recB.x*64 + hi*8);
    short8 ng3 = *reinterpret_cast<const short8*>(h + (size_t)recB.x*64 + (4+hi)*8);
    // record for t+2
    int tC = (t+2 < t1)? t+2 : ((t+1 < t1)? t+1 : t);
    int2 recC = edges[tC*16 + lo];
    int  dvC  = dsts[tC*16 + lo];

    unsigned ev = (unsigned)recA.y;
    short8 b4v = {0,0,0,0,0,0,0,0};
    if (hi==0){ b4v[0] = (short)(ev & 0xffffu); b4v[1] = (short)(ev >> 16); }

    // layer1 swapped
    floatx4 a1[4];
    #pragma unroll
    for (int ct=0;ct<4;ct++) a1[ct]=(floatx4){bb1[ct][0],bb1[ct][1],bb1[ct][2],bb1[ct][3]};
    __builtin_amdgcn_s_setprio(1);
    #pragma unroll
    for (int ct=0;ct<4;ct++) a1[ct] = __builtin_amdgcn_mfma_f32_16x16x32_bf16(w1[(0*4+ct)*64], cg0, a1[ct],0,0,0);
    #pragma unroll
    for (int ct=0;ct<4;ct++) a1[ct] = __builtin_amdgcn_mfma_f32_16x16x32_bf16(w1[(1*4+ct)*64], cg1, a1[ct],0,0,0);
    #pragma unroll
    for (int ct=0;ct<4;ct++) a1[ct] = __builtin_amdgcn_mfma_f32_16x16x32_bf16(w1[(2*4+ct)*64], cg2, a1[ct],0,0,0);
    #pragma unroll
    for (int ct=0;ct<4;ct++) a1[ct] = __builtin_amdgcn_mfma_f32_16x16x32_bf16(w1[(3*4+ct)*64], cg3, a1[ct],0,0,0);
    #pragma unroll
    for (int ct=0;ct<4;ct++) a1[ct] = __builtin_amdgcn_mfma_f32_16x16x32_bf16(w1[(4*4+ct)*64], b4v, a1[ct],0,0,0);
    __builtin_amdgcn_s_setprio(0);

    // in-register transpose + relu (r7 lane math) with packed HW bf16 convert
    unsigned hu0[4], hu1[4];
    #pragma unroll
    for (int jp=0;jp<4;jp++){
      int jj = jp*2;
      int Ls = ((lane&16)<<1) | ((jj>>2)<<4) | lo;
      float a0 = __shfl(a1[0][jj&3], Ls);
      float b0 = __shfl(a1[1][jj&3], Ls);
      float a1x = __shfl(a1[0][(jj+1)&3], Ls);
      float b1x = __shfl(a1[1][(jj+1)&3], Ls);
      float x0 = (lane>=32)? b0 : a0;
      float x1 = (lane>=32)? b1x : a1x;
      hu0[jp] = cvt_pk_bf16(fmaxf(x0,0.f), fmaxf(x1,0.f));
      float c0 = __shfl(a1[2][jj&3], Ls);
      float d0 = __shfl(a1[3][jj&3], Ls);
      float c1 = __shfl(a1[2][(jj+1)&3], Ls);
      float d1 = __shfl(a1[3][(jj+1)&3], Ls);
      float y0 = (lane>=32)? d0 : c0;
      float y1 = (lane>=32)? d1 : c1;
      hu1[jp] = cvt_pk_bf16(fmaxf(y0,0.f), fmaxf(y1,0.f));
    }
    uintx4 hv0 = {hu0[0],hu0[1],hu0[2],hu0[3]};
    uintx4 hv1 = {hu1[0],hu1[1],hu1[2],hu1[3]};
    short8 ha0 = *reinterpret_cast<short8*>(&hv0);
    short8 ha1 = *reinterpret_cast<short8*>(&hv1);

    // layer2 swapped: lane (hi,lo) tile ct holds m[t*16+lo][ct*16+hi*4+j] -> 8B store
    floatx4 mt[4];
    #pragma unroll
    for (int ct=0;ct<4;ct++) mt[ct]=(floatx4){bb2s[ct][0],bb2s[ct][1],bb2s[ct][2],bb2s[ct][3]};
    __builtin_amdgcn_s_setprio(1);
    #pragma unroll
    for (int ct=0;ct<4;ct++) mt[ct] = __builtin_amdgcn_mfma_f32_16x16x32_bf16(w2[(0*4+ct)*64], ha0, mt[ct],0,0,0);
    #pragma unroll
    for (int ct=0;ct<4;ct++) mt[ct] = __builtin_amdgcn_mfma_f32_16x16x32_bf16(w2[(1*4+ct)*64], ha1, mt[ct],0,0,0);
    __builtin_amdgcn_s_setprio(0);

    #pragma unroll
    for (int ct=0;ct<4;ct++){
      uint2 pk = make_uint2(cvt_pk_bf16(mt[ct][0], mt[ct][1]),
                            cvt_pk_bf16(mt[ct][2], mt[ct][3]));
      *reinterpret_cast<uint2*>(m_s + (size_t)(t*16+lo)*64 + ct*16 + hi*4) = pk;
    }

    recA = recB; dvA = dvB; recB = recC; dvB = dvC;
    cg0 = ng0; cg1 = ng1; cg2 = ng2; cg3 = ng3;
  }
}

// ------------------------- node update kernel (shuffle-free + cvt_pk) -------
__launch_bounds__(256)
__global__ void k_update(const ushort_t* __restrict__ m_s,
                         const int* __restrict__ rowptr,
                         const ushort_t* __restrict__ hin,
                         const ushort_t* __restrict__ w1f, const ushort_t* __restrict__ w2f,
                         const float* __restrict__ b1, const float* __restrict__ b2,
                         ushort_t* __restrict__ emb, ushort_t* __restrict__ hout){
  __shared__ short xl[4*10*64*8];
  int n0 = xcd_swz(blockIdx.x, NBLK_U)*64;
  int tid = threadIdx.x;
  int wv = tid>>6, lane = tid&63;
  int b = lane>>4;                 // node index within batch (0..3)
  int c4 = (lane&15)*4;            // 4 channels per lane
  int n0w = n0 + wv*16;

  int rp_l;
  {
    int o = lane; if (o > 17) o = 17;
    int idx = n0w + o; if (idx > NN) idx = NN;
    rp_l = rowptr[idx];
  }

  for (int batch=0; batch<4; batch++){
    int q = batch*4 + b;
    int n = n0w + q;
    bool nv = n < NN;
    int rp0 = __shfl(rp_l, q);
    int rp1 = __shfl(rp_l, q+1);
    int deg = rp1 - rp0;

    float sm0=0.f,sm1=0.f,sm2=0.f,sm3=0.f;
    float sq0=0.f,sq1=0.f,sq2=0.f,sq3=0.f;
    float mn0=3.4e38f,mn1=3.4e38f,mn2=3.4e38f,mn3=3.4e38f;
    float mx0=-3.4e38f,mx1=-3.4e38f,mx2=-3.4e38f,mx3=-3.4e38f;

    const ushort_t* mp = m_s + (size_t)rp0*64 + c4;

#define ACC4(U) { \
      float v0=bf2f_lo((U).x), v1=bf2f_hi((U).x), v2=bf2f_lo((U).y), v3=bf2f_hi((U).y); \
      sm0+=v0; sq0+=v0*v0; mn0=fminf(mn0,v0); mx0=fmaxf(mx0,v0); \
      sm1+=v1; sq1+=v1*v1; mn1=fminf(mn1,v1); mx1=fmaxf(mx1,v1); \
      sm2+=v2; sq2+=v2*v2; mn2=fminf(mn2,v2); mx2=fmaxf(mx2,v2); \
      sm3+=v3; sq3+=v3*v3; mn3=fminf(mn3,v3); mx3=fmaxf(mx3,v3); }

    int i = 0;
    for (; i + 2 <= deg; i += 2){
      uint2 ua = *reinterpret_cast<const uint2*>(mp + (size_t)i*64);
      uint2 ub = *reinterpret_cast<const uint2*>(mp + (size_t)(i+1)*64);
      ACC4(ua); ACC4(ub);
    }
    if (i < deg){
      uint2 ua = *reinterpret_cast<const uint2*>(mp + (size_t)i*64);
      ACC4(ua);
    }
#undef ACC4

    float invc = 1.f / (float)(deg>0?deg:1);
    float me0=sm0*invc, me1=sm1*invc, me2=sm2*invc, me3=sm3*invc;
    float sd0=__fsqrt_rn(fmaxf(sq0*invc-me0*me0,0.f)+1e-5f);
    float sd1=__fsqrt_rn(fmaxf(sq1*invc-me1*me1,0.f)+1e-5f);
    float sd2=__fsqrt_rn(fmaxf(sq2*invc-me2*me2,0.f)+1e-5f);
    float sd3=__fsqrt_rn(fmaxf(sq3*invc-me3*me3,0.f)+1e-5f);
    if (deg<=0){ mn0=mn1=mn2=mn3=0.f; mx0=mx1=mx2=mx3=0.f; }

    // stats -> A-fragment layout via packed converts (uint2 = short4)
    auto stw2 = [&](int s, unsigned u01, unsigned u23){
      int k0 = s*64 + c4;
      int ks = k0>>5, g2=(k0>>3)&3, j0 = c4&7;
      *reinterpret_cast<uint2*>(&xl[(((wv*10+ks)*64 + g2*16 + q)<<3) + j0]) = make_uint2(u01,u23);
    };
    stw2(0, cvt_pk_bf16(sd0,sd1), cvt_pk_bf16(sd2,sd3));
    stw2(1, cvt_pk_bf16(mn0,mn1), cvt_pk_bf16(mn2,mn3));
    stw2(2, cvt_pk_bf16(mx0,mx1), cvt_pk_bf16(mx2,mx3));
    stw2(3, cvt_pk_bf16(me0,me1), cvt_pk_bf16(me2,me3));
    uint2 hu = {0u,0u};
    if (nv) hu = *reinterpret_cast<const uint2*>(hin + (size_t)n*64 + c4);
    stw2(4, hu.x, hu.y);
  }
  __syncthreads();

  int r0 = (lane>>4)*4;
  const short8* xw = reinterpret_cast<const short8*>(xl) + wv*10*64 + lane;
  const short8* w1 = reinterpret_cast<const short8*>(w1f) + lane;
  floatx4 acc[4];
  #pragma unroll
  for (int ct=0;ct<4;ct++){ float bb=b1[ct*16+(lane&15)]; acc[ct]=(floatx4){bb,bb,bb,bb}; }
  #pragma unroll
  for (int ks=0; ks<10; ks++){
    short8 a = xw[ks*64];
    #pragma unroll
    for (int ct=0;ct<4;ct++)
      acc[ct] = __builtin_amdgcn_mfma_f32_16x16x32_bf16(a, w1[(ks*4+ct)*64], acc[ct], 0,0,0);
  }
  __syncthreads();
  #pragma unroll
  for (int ct=0; ct<4; ct++){
    int colk = ct*16 + (lane&15);
    int ks2 = colk>>5, g2=(colk>>3)&3, j2=colk&7;
    #pragma unroll
    for (int j=0;j<4;j++){
      float rv = fmaxf(acc[ct][j],0.f);
      xl[(((wv*10+ks2)*64 + g2*16 + (r0+j))<<3) + j2] = (short)(cvt_pk_bf16(rv,rv) & 0xffffu);
    }
  }
  __syncthreads();

  const short8* w2 = reinterpret_cast<const short8*>(w2f) + lane;
  floatx4 mac[4];
  #pragma unroll
  for (int ct=0;ct<4;ct++){ float bb=b2[ct*16+(lane&15)]; mac[ct]=(floatx4){bb,bb,bb,bb}; }
  #pragma unroll
  for (int ks=0; ks<2; ks++){
    short8 a = xw[ks*64];
    #pragma unroll
    for (int ct=0;ct<4;ct++)
      mac[ct] = __builtin_amdgcn_mfma_f32_16x16x32_bf16(a, w2[(ks*4+ct)*64], mac[ct], 0,0,0);
  }
  #pragma unroll
  for (int ct=0;ct<4;ct++){
    int col = ct*16+(lane&15);
    #pragma unroll
    for (int j=0;j<4;j++){
      int n = n0 + wv*16 + r0 + j;
      if (n < NN){
        float v = mac[ct][j];
        unsigned pk = cvt_pk_bf16(v, fmaxf(v,0.f));   // lo=emb, hi=relu
        emb[(size_t)n*64+col]  = (ushort_t)(pk & 0xffffu);
        hout[(size_t)n*64+col] = (ushort_t)(pk >> 16);
      }
    }
  }
}

// ------------------------- readout kernel (2-deep pipeline, float4 out) -----
__launch_bounds__(256)
__global__ void k_readout(const ushort_t* __restrict__ emb,
                          const int* __restrict__ srcI, const int* __restrict__ dstI,
                          const float* __restrict__ ef,
                          const ushort_t* __restrict__ w1f,
                          const float* __restrict__ b1,
                          const float* __restrict__ w2, const float* __restrict__ b2,
                          float* __restrict__ out){
  int tid = threadIdx.x;
  int wv = tid>>6, lane = tid&63;
  int lo = lane&15, g = lane>>4;
  int wave = blockIdx.x*4 + wv;
  int t0 = wave*TPW;
  if (t0 >= NTILES) return;
  int t1 = t0 + TPW; if (t1 > NTILES) t1 = NTILES;

  const short8* w1 = reinterpret_cast<const short8*>(w1f) + lane;
  float bia[4];
  #pragma unroll
  for (int ct=0;ct<4;ct++) bia[ct] = b1[ct*16+lo];
  float w2v[4];
  #pragma unroll
  for (int ct=0;ct<4;ct++) w2v[ct] = w2[ct*16+lo];
  float bb2 = b2[0];
  int r0 = g*4;

  // prologue: indices+gathers for t0, indices for t0+1
  int pA = t0*16 + lo;
  int svA = srcI[pA], dvA = dstI[pA];
  float2 fA = reinterpret_cast<const float2*>(ef)[pA];
  short8 v0_ = *reinterpret_cast<const short8*>(emb + (size_t)svA*64 + g*8);
  short8 v1_ = *reinterpret_cast<const short8*>(emb + (size_t)svA*64 + (4+g)*8);
  short8 v2_ = *reinterpret_cast<const short8*>(emb + (size_t)dvA*64 + g*8);
  short8 v3_ = *reinterpret_cast<const short8*>(emb + (size_t)dvA*64 + (4+g)*8);
  int tB = (t0+1 < t1)? t0+1 : t0;
  int pB = tB*16 + lo;
  int svB = srcI[pB], dvB = dstI[pB];
  float2 fB = reinterpret_cast<const float2*>(ef)[pB];

  for (int t = t0; t < t1; ++t){
    // issue gathers for t+1 at top (full-body latency cover)
    short8 n0 = *reinterpret_cast<const short8*>(emb + (size_t)svB*64 + g*8);
    short8 n1 = *reinterpret_cast<const short8*>(emb + (size_t)svB*64 + (4+g)*8);
    short8 n2 = *reinterpret_cast<const short8*>(emb + (size_t)dvB*64 + g*8);
    short8 n3 = *reinterpret_cast<const short8*>(emb + (size_t)dvB*64 + (4+g)*8);
    int tC = (t+2 < t1)? t+2 : ((t+1 < t1)? t+1 : t);
    int pC = tC*16 + lo;
    int svC = srcI[pC], dvC = dstI[pC];
    float2 fC = reinterpret_cast<const float2*>(ef)[pC];

    unsigned evc = cvt_pk_bf16(fA.x, fA.y);
    short8 b4v = {0,0,0,0,0,0,0,0};
    if (g==0){ b4v[0] = (short)(evc & 0xffffu); b4v[1] = (short)(evc >> 16); }

    floatx4 acc[4];
    #pragma unroll
    for (int ct=0;ct<4;ct++) acc[ct]=(floatx4){bia[ct],bia[ct],bia[ct],bia[ct]};
    __builtin_amdgcn_s_setprio(1);
    #pragma unroll
    for (int ct=0;ct<4;ct++) acc[ct] = __builtin_amdgcn_mfma_f32_16x16x32_bf16(v0_, w1[(0*4+ct)*64], acc[ct],0,0,0);
    #pragma unroll
    for (int ct=0;ct<4;ct++) acc[ct] = __builtin_amdgcn_mfma_f32_16x16x32_bf16(v1_, w1[(1*4+ct)*64], acc[ct],0,0,0);
    #pragma unroll
    for (int ct=0;ct<4;ct++) acc[ct] = __builtin_amdgcn_mfma_f32_16x16x32_bf16(v2_, w1[(2*4+ct)*64], acc[ct],0,0,0);
    #pragma unroll
    for (int ct=0;ct<4;ct++) acc[ct] = __builtin_amdgcn_mfma_f32_16x16x32_bf16(v3_, w1[(3*4+ct)*64], acc[ct],0,0,0);
    #pragma unroll
    for (int ct=0;ct<4;ct++) acc[ct] = __builtin_amdgcn_mfma_f32_16x16x32_bf16(b4v, w1[(4*4+ct)*64], acc[ct],0,0,0);
    __builtin_amdgcn_s_setprio(0);

    float part[4];
    #pragma unroll
    for (int j=0;j<4;j++){
      float pj = 0.f;
      #pragma unroll
      for (int ct=0;ct<4;ct++) pj += fmaxf(acc[ct][j],0.f)*w2v[ct];
      part[j] = pj;
    }
    #pragma unroll
    for (int m=1;m<16;m<<=1){
      #pragma unroll
      for (int j=0;j<4;j++) part[j] += __shfl_xor(part[j], m, 64);
    }
    if (lo==0){
      float4 o = make_float4(part[0]+bb2, part[1]+bb2, part[2]+bb2, part[3]+bb2);
      *reinterpret_cast<float4*>(out + t*16 + r0) = o;
    }

    v0_=n0; v1_=n1; v2_=n2; v3_=n3;
    fA = fB; fB = fC;
    svB = svC; dvB = dvC;
  }
}

// ------------------------- launcher -------------------------
extern "C" void kernel_launch(void* const* d_in, const int* in_sizes, int n_in,
                              void* d_out, int out_size, void* d_ws, size_t ws_size,
                              hipStream_t stream){
  const float* nf    = (const float*)d_in[0];
  const float* ef    = (const float*)d_in[1];
  const float* initW = (const float*)d_in[2];
  const float* initb = (const float*)d_in[3];
  const float* msgW1 = (const float*)d_in[4];
  const float* msgb1 = (const float*)d_in[5];
  const float* msgW2 = (const float*)d_in[6];
  const float* msgb2 = (const float*)d_in[7];
  const float* updW1 = (const float*)d_in[8];
  const float* updb1 = (const float*)d_in[9];
  const float* updW2 = (const float*)d_in[10];
  const float* updb2 = (const float*)d_in[11];
  const float* roW1  = (const float*)d_in[12];
  const float* rob1  = (const float*)d_in[13];
  const float* roW2  = (const float*)d_in[14];
  const float* rob2  = (const float*)d_in[15];
  const int*   eidx  = (const int*)d_in[16];
  const int* srcI = eidx;
  const int* dstI = eidx + NE;
  float* out = (float*)d_out;

  char* base = (char*)d_ws; size_t off = 0;
  auto alloc = [&](size_t b)->char*{ char* p = base + off; off = (off + b + 255) & ~(size_t)255; return p; };
  int* cnt    = (int*)alloc((size_t)NN*4);
  int* fill   = (int*)alloc((size_t)NN*4);
  int* rowptr = (int*)alloc((size_t)(NN+1)*4);
  int* bsum   = (int*)alloc(512*4);
  int* bfill  = (int*)alloc((size_t)NBUK*4);
  int4* btmp  = (int4*)alloc((size_t)NE*16);
  int2* edges = (int2*)alloc((size_t)NE*8);
  int* dsts   = (int*)alloc((size_t)NE*4);
  ushort_t* hA  = (ushort_t*)alloc((size_t)NN*64*2);
  ushort_t* hB  = (ushort_t*)alloc((size_t)NN*64*2);
  ushort_t* emb = (ushort_t*)alloc((size_t)NN*64*2);
  ushort_t* m_s = (ushort_t*)alloc((size_t)NE*64*2);
  ushort_t* msgW1f = (ushort_t*)alloc(5*2048*2);
  ushort_t* msgW2f = (ushort_t*)alloc(2*2048*2);
  ushort_t* updW1f = (ushort_t*)alloc(10*2048*2);
  ushort_t* updW2f = (ushort_t*)alloc(2*2048*2);
  ushort_t* roW1f  = (ushort_t*)alloc(5*2048*2);
  (void)ws_size; (void)in_sizes; (void)n_in; (void)out_size;

  hipMemsetAsync(cnt, 0, (size_t)NN*4, stream);
  int nb = (NN+255)/256;
  k_count<<<(NE/4+255)/256,256,0,stream>>>(dstI,cnt);
  k_scan1<<<nb,256,0,stream>>>(cnt,bsum);
  k_scan2<<<1,512,0,stream>>>(bsum,nb);
  k_scan3<<<nb,256,0,stream>>>(cnt,bsum,rowptr);
  hipMemcpyAsync(fill, rowptr, (size_t)NN*4, hipMemcpyDeviceToDevice, stream);
  k_filldst<<<nb,256,0,stream>>>(rowptr,dsts);
  k_binit<<<(NBUK+255)/256,256,0,stream>>>(rowptr,bfill);
  k_bin<<<NBLK_BIN,256,0,stream>>>(srcI,dstI,ef,bfill,btmp);
  k_sort2<<<NBUK,256,0,stream>>>(btmp,rowptr,fill,edges);
  k_wprep<<<(5*2048+255)/256,256,0,stream>>>(msgW1,msgW1f,130,5*2048);
  k_wprep<<<(2*2048+255)/256,256,0,stream>>>(msgW2,msgW2f,64,2*2048);
  k_wprep<<<(10*2048+255)/256,256,0,stream>>>(updW1,updW1f,320,10*2048);
  k_wprep<<<(2*2048+255)/256,256,0,stream>>>(updW2,updW2f,64,2*2048);
  k_wprep<<<(5*2048+255)/256,256,0,stream>>>(roW1,roW1f,130,5*2048);
  k_init<<<(NN*64+255)/256,256,0,stream>>>(nf,initW,initb,hA,emb);

  for (int it=0; it<ITERS; it++){
    const ushort_t* hin = (it&1)? hB : hA;
    ushort_t* hout      = (it&1)? hA : hB;
    k_edge<<<NBLK_E,256,0,stream>>>(hin,edges,dsts,msgW1f,msgW2f,msgb1,msgb2,m_s);
    k_update<<<NBLK_U,256,0,stream>>>(m_s,rowptr,hin,updW1f,updW2f,updb1,updb2,emb,hout);
  }
  k_readout<<<NBLK_E,256,0,stream>>>(emb,srcI,dstI,ef,roW1f,rob1,roW2,rob2,out);
}

// Round 19
// 817.162 us; speedup vs baseline: 1.2746x; 1.2746x over previous
//
#include <hip/hip_runtime.h>

#define NN 100000
#define NE 1200000
#define ITERS 5
#define NTILES (NE/16)          // 75000 edge tiles
#define TPW 16                  // tiles per wave (k_edge)
#define NWAVES ((NTILES+TPW-1)/TPW)
#define NBLK_E ((NWAVES+3)/4)
#define TPW_R 8                 // tiles per wave (k_readout: lighter prologue)
#define NWAVES_R ((NTILES+TPW_R-1)/TPW_R)
#define NBLK_R ((NWAVES_R+3)/4)
#define NBLK_U ((NN+63)/64)
#define NBUK ((NN+511)/512)     // 196 dst-buckets
#define BINSZ 4096
#define NBLK_BIN ((NE+BINSZ-1)/BINSZ)

typedef __attribute__((ext_vector_type(8))) short short8;
typedef __attribute__((ext_vector_type(4))) short short4_t;
typedef __attribute__((ext_vector_type(4))) float floatx4;
typedef unsigned short ushort_t;

__device__ inline ushort_t f2bf(float f){
  unsigned u = __float_as_uint(f);
  unsigned r = (u + 0x7fffu + ((u>>16)&1u)) >> 16;
  return (ushort_t)r;
}
__device__ inline float bf2f(ushort_t u){ return __uint_as_float(((unsigned)u)<<16); }
__device__ inline float bf2f_lo(unsigned u){ return __uint_as_float(u<<16); }
__device__ inline float bf2f_hi(unsigned u){ return __uint_as_float(u & 0xffff0000u); }

// bijective XCD-chunked swizzle (m204)
__device__ inline int xcd_swz(int orig, int nwg){
  int q = nwg >> 3, r = nwg & 7;
  int x = orig & 7, i = orig >> 3;
  return (x < r ? x*(q+1) : r*(q+1) + (x-r)*q) + i;
}

// ------------------------- prep: counting sort by dst -------------------------
__global__ void k_count(const int* __restrict__ dst, int* __restrict__ cnt){
  int base = (blockIdx.x*256 + threadIdx.x)*4;
  if (base >= NE) return;
  int4 d4 = *reinterpret_cast<const int4*>(dst + base);
  atomicAdd(&cnt[d4.x],1); atomicAdd(&cnt[d4.y],1);
  atomicAdd(&cnt[d4.z],1); atomicAdd(&cnt[d4.w],1);
}

__global__ void k_scan1(const int* __restrict__ cnt, int* __restrict__ bsum){
  __shared__ int s[256];
  int t = threadIdx.x; int i = blockIdx.x*256 + t;
  s[t] = (i < NN) ? cnt[i] : 0; __syncthreads();
  for (int off=128; off>0; off>>=1){ if (t<off) s[t]+=s[t+off]; __syncthreads(); }
  if (t==0) bsum[blockIdx.x] = s[0];
}

__global__ void k_scan2(int* bsum, int nb){
  __shared__ int s[512];
  int t = threadIdx.x;
  int v = (t<nb)? bsum[t] : 0;
  s[t]=v; __syncthreads();
  for (int off=1; off<512; off<<=1){
    int x = (t>=off)? s[t-off] : 0; __syncthreads();
    s[t]+=x; __syncthreads();
  }
  if (t<nb) bsum[t] = s[t]-v; // exclusive
}

__global__ void k_scan3(const int* __restrict__ cnt, const int* __restrict__ bsum, int* __restrict__ rowptr){
  __shared__ int s[256];
  int t=threadIdx.x; int i = blockIdx.x*256+t;
  int v = (i<NN)? cnt[i]:0;
  s[t]=v; __syncthreads();
  for (int off=1; off<256; off<<=1){
    int x = (t>=off)? s[t-off] : 0; __syncthreads();
    s[t] += x; __syncthreads();
  }
  if (i<NN) rowptr[i] = bsum[blockIdx.x] + s[t] - v;
  if (i==0) rowptr[NN] = NE;
}

// dsts[pos] = node id, reconstructed COALESCED from rowptr (sorted by dst)
__global__ void k_filldst(const int* __restrict__ rowptr, int* __restrict__ dsts){
  int n = blockIdx.x*256 + threadIdx.x;
  if (n >= NN) return;
  int a = rowptr[n], b = rowptr[n+1];
  for (int p = a; p < b; ++p) dsts[p] = n;
}

// bucket fill seeds: bucket b's region starts at rowptr[b*512]
__global__ void k_binit(const int* __restrict__ rowptr, int* __restrict__ bfill){
  int b = blockIdx.x*256 + threadIdx.x;
  if (b >= NBUK) return;
  int n = b*512; if (n > NN) n = NN;
  bfill[b] = rowptr[n];
}

// pass 1: coarse-bin edges by dst>>9, bucket-grouped writes (low line ampl.)
__global__ void k_bin(const int* __restrict__ src, const int* __restrict__ dst,
                      const float* __restrict__ ef,
                      int* __restrict__ bfill, int4* __restrict__ btmp){
  __shared__ int hist[NBUK];
  __shared__ int base[NBUK];
  int t = threadIdx.x;
  for (int i=t; i<NBUK; i+=256) hist[i]=0;
  __syncthreads();
  int e0 = blockIdx.x*BINSZ + t;
  #pragma unroll
  for (int k=0;k<BINSZ/256;k++){
    int e = e0 + k*256;
    if (e < NE) atomicAdd(&hist[dst[e]>>9], 1);
  }
  __syncthreads();
  for (int i=t; i<NBUK; i+=256){
    int c = hist[i];
    base[i] = (c>0)? atomicAdd(&bfill[i], c) : 0;
    hist[i] = 0;
  }
  __syncthreads();
  #pragma unroll
  for (int k=0;k<BINSZ/256;k++){
    int e = e0 + k*256;
    if (e < NE){
      int d = dst[e];
      int b = d>>9;
      int off = atomicAdd(&hist[b],1);
      float2 f = reinterpret_cast<const float2*>(ef)[e];
      int efp = (int)((unsigned)f2bf(f.x)|((unsigned)f2bf(f.y)<<16));
      btmp[base[b]+off] = make_int4(src[e], d, efp, 0);
    }
  }
}

// pass 2: fine scatter within one bucket (stores land in a ~50KB L2-local window)
__global__ void k_sort2(const int4* __restrict__ btmp, const int* __restrict__ rowptr,
                        int* __restrict__ fill, int2* __restrict__ edges){
  int b = blockIdx.x;
  int nlo = b*512; if (nlo > NN) nlo = NN;
  int nhi = (b+1)*512; if (nhi > NN) nhi = NN;
  int plo = rowptr[nlo], phi = rowptr[nhi];
  for (int p = plo + threadIdx.x; p < phi; p += 256){
    int4 r = btmp[p];
    int pos = atomicAdd(&fill[r.y],1);
    edges[pos] = make_int2(r.x, r.z);
  }
}

// weights -> bf16 MFMA B-fragment order (also valid as A-fragment of W^T)
__global__ void k_wprep(const float* __restrict__ W, ushort_t* __restrict__ frag, int Ksrc, int total){
  int t = blockIdx.x*256+threadIdx.x;
  if (t>=total) return;
  int j = t&7, l=(t>>3)&63, ct=(t>>9)&3, ks=t>>11;
  int k = ks*32 + ((l>>4)<<3) + j;
  int col = ct*16 + (l&15);
  float v = (k<Ksrc)? W[k*64+col] : 0.f;
  frag[t] = f2bf(v);
}

__global__ void k_init(const float* __restrict__ nf, const float* __restrict__ W, const float* __restrict__ b,
                       ushort_t* __restrict__ hA, ushort_t* __restrict__ emb){
  int t = blockIdx.x*256+threadIdx.x;
  if (t >= NN*64) return;
  int n=t>>6, c=t&63;
  float a = b[c];
  a += nf[n*3+0]*W[0*64+c];
  a += nf[n*3+1]*W[1*64+c];
  a += nf[n*3+2]*W[2*64+c];
  emb[t] = f2bf(a);
  hA[t] = f2bf(fmaxf(a,0.f));
}

// ------------------------- edge message kernel ------------------------------
// r17-proven body (822us): both layers swapped; r7-verified shuffle transpose;
// packed 8B channel-major stores; 2-deep pipeline; int2 records + coalesced
// dsts; setprio around MFMA clusters; XCD swizzle. Plain f2bf (m240: hand-
// written cvt_pk asm breaks the scheduler, -27% measured r18).
__launch_bounds__(256)
__global__ void k_edge(const ushort_t* __restrict__ h,
                       const int2* __restrict__ edges, const int* __restrict__ dsts,
                       const ushort_t* __restrict__ w1f, const ushort_t* __restrict__ w2f,
                       const float* __restrict__ b1, const float* __restrict__ b2,
                       ushort_t* __restrict__ m_s){
  int tid = threadIdx.x;
  int wv = tid>>6, lane = tid&63;
  int lo = lane&15, hi = lane>>4;
  int wave = xcd_swz(blockIdx.x, NBLK_E)*4 + wv;
  int t0 = wave*TPW;
  if (t0 >= NTILES) return;
  int t1 = t0 + TPW; if (t1 > NTILES) t1 = NTILES;

  const short8* w1 = reinterpret_cast<const short8*>(w1f) + lane;
  const short8* w2 = reinterpret_cast<const short8*>(w2f) + lane;

  float bb1[4][4], bb2s[4][4];
  #pragma unroll
  for (int ct=0;ct<4;ct++)
    #pragma unroll
    for (int jr=0;jr<4;jr++){
      bb1[ct][jr]  = b1[ct*16 + hi*4 + jr];
      bb2s[ct][jr] = b2[ct*16 + hi*4 + jr];
    }

  // prologue: rec(t0)+dst(t0) + gathers(t0), rec(t0+1)+dst(t0+1)
  int2 recA = edges[t0*16 + lo];
  int  dvA  = dsts[t0*16 + lo];
  short8 cg0 = *reinterpret_cast<const short8*>(h + (size_t)dvA*64 + hi*8);
  short8 cg1 = *reinterpret_cast<const short8*>(h + (size_t)dvA*64 + (4+hi)*8);
  short8 cg2 = *reinterpret_cast<const short8*>(h + (size_t)recA.x*64 + hi*8);
  short8 cg3 = *reinterpret_cast<const short8*>(h + (size_t)recA.x*64 + (4+hi)*8);
  int tB = (t0+1 < t1)? t0+1 : t0;
  int2 recB = edges[tB*16 + lo];
  int  dvB  = dsts[tB*16 + lo];

  for (int t = t0; t < t1; ++t){
    // issue gathers for t+1 NOW (consumed next iteration -> full-body cover)
    short8 ng0 = *reinterpret_cast<const short8*>(h + (size_t)dvB*64 + hi*8);
    short8 ng1 = *reinterpret_cast<const short8*>(h + (size_t)dvB*64 + (4+hi)*8);
    short8 ng2 = *reinterpret_cast<const short8*>(h + (size_t)recB.x*64 + hi*8);
    short8 ng3 = *reinterpret_cast<const short8*>(h + (size_t)recB.x*64 + (4+hi)*8);
    // record for t+2
    int tC = (t+2 < t1)? t+2 : ((t+1 < t1)? t+1 : t);
    int2 recC = edges[tC*16 + lo];
    int  dvC  = dsts[tC*16 + lo];

    unsigned ev = (unsigned)recA.y;
    short8 b4v = {0,0,0,0,0,0,0,0};
    if (hi==0){ b4v[0] = (short)(ev & 0xffffu); b4v[1] = (short)(ev >> 16); }

    // layer1 swapped
    floatx4 a1[4];
    #pragma unroll
    for (int ct=0;ct<4;ct++) a1[ct]=(floatx4){bb1[ct][0],bb1[ct][1],bb1[ct][2],bb1[ct][3]};
    __builtin_amdgcn_s_setprio(1);
    #pragma unroll
    for (int ct=0;ct<4;ct++) a1[ct] = __builtin_amdgcn_mfma_f32_16x16x32_bf16(w1[(0*4+ct)*64], cg0, a1[ct],0,0,0);
    #pragma unroll
    for (int ct=0;ct<4;ct++) a1[ct] = __builtin_amdgcn_mfma_f32_16x16x32_bf16(w1[(1*4+ct)*64], cg1, a1[ct],0,0,0);
    #pragma unroll
    for (int ct=0;ct<4;ct++) a1[ct] = __builtin_amdgcn_mfma_f32_16x16x32_bf16(w1[(2*4+ct)*64], cg2, a1[ct],0,0,0);
    #pragma unroll
    for (int ct=0;ct<4;ct++) a1[ct] = __builtin_amdgcn_mfma_f32_16x16x32_bf16(w1[(3*4+ct)*64], cg3, a1[ct],0,0,0);
    #pragma unroll
    for (int ct=0;ct<4;ct++) a1[ct] = __builtin_amdgcn_mfma_f32_16x16x32_bf16(w1[(4*4+ct)*64], b4v, a1[ct],0,0,0);
    __builtin_amdgcn_s_setprio(0);

    // in-register transpose + relu (verified r7)
    short8 ha0, ha1;
    #pragma unroll
    for (int jj=0;jj<8;jj++){
      int Ls = ((lane&16)<<1) | ((jj>>2)<<4) | lo;
      float va = __shfl(a1[0][jj&3], Ls);
      float vb = __shfl(a1[1][jj&3], Ls);
      float v0 = (lane>=32)? vb : va;
      ha0[jj] = (short)f2bf(fmaxf(v0,0.f));
      float vc = __shfl(a1[2][jj&3], Ls);
      float vd = __shfl(a1[3][jj&3], Ls);
      float v1 = (lane>=32)? vd : vc;
      ha1[jj] = (short)f2bf(fmaxf(v1,0.f));
    }

    // layer2 swapped: lane (hi,lo) tile ct holds m[t*16+lo][ct*16+hi*4+j] -> 8B store
    floatx4 mt[4];
    #pragma unroll
    for (int ct=0;ct<4;ct++) mt[ct]=(floatx4){bb2s[ct][0],bb2s[ct][1],bb2s[ct][2],bb2s[ct][3]};
    __builtin_amdgcn_s_setprio(1);
    #pragma unroll
    for (int ct=0;ct<4;ct++) mt[ct] = __builtin_amdgcn_mfma_f32_16x16x32_bf16(w2[(0*4+ct)*64], ha0, mt[ct],0,0,0);
    #pragma unroll
    for (int ct=0;ct<4;ct++) mt[ct] = __builtin_amdgcn_mfma_f32_16x16x32_bf16(w2[(1*4+ct)*64], ha1, mt[ct],0,0,0);
    __builtin_amdgcn_s_setprio(0);

    #pragma unroll
    for (int ct=0;ct<4;ct++){
      short4_t pk = {(short)f2bf(mt[ct][0]), (short)f2bf(mt[ct][1]),
                     (short)f2bf(mt[ct][2]), (short)f2bf(mt[ct][3])};
      *reinterpret_cast<short4_t*>(m_s + (size_t)(t*16+lo)*64 + ct*16 + hi*4) = pk;
    }

    recA = recB; dvA = dvB; recB = recC; dvB = dvC;
    cg0 = ng0; cg1 = ng1; cg2 = ng2; cg3 = ng3;
  }
}

// ------------------------- node update kernel (shuffle-free, proven r11/r14) -
__launch_bounds__(256)
__global__ void k_update(const ushort_t* __restrict__ m_s,
                         const int* __restrict__ rowptr,
                         const ushort_t* __restrict__ hin,
                         const ushort_t* __restrict__ w1f, const ushort_t* __restrict__ w2f,
                         const float* __restrict__ b1, const float* __restrict__ b2,
                         ushort_t* __restrict__ emb, ushort_t* __restrict__ hout){
  __shared__ short xl[4*10*64*8];
  int n0 = xcd_swz(blockIdx.x, NBLK_U)*64;
  int tid = threadIdx.x;
  int wv = tid>>6, lane = tid&63;
  int b = lane>>4;                 // node index within batch (0..3)
  int c4 = (lane&15)*4;            // 4 channels per lane
  int n0w = n0 + wv*16;

  int rp_l;
  {
    int o = lane; if (o > 17) o = 17;
    int idx = n0w + o; if (idx > NN) idx = NN;
    rp_l = rowptr[idx];
  }

  for (int batch=0; batch<4; batch++){
    int q = batch*4 + b;
    int n = n0w + q;
    bool nv = n < NN;
    int rp0 = __shfl(rp_l, q);
    int rp1 = __shfl(rp_l, q+1);
    int deg = rp1 - rp0;

    float sm0=0.f,sm1=0.f,sm2=0.f,sm3=0.f;
    float sq0=0.f,sq1=0.f,sq2=0.f,sq3=0.f;
    float mn0=3.4e38f,mn1=3.4e38f,mn2=3.4e38f,mn3=3.4e38f;
    float mx0=-3.4e38f,mx1=-3.4e38f,mx2=-3.4e38f,mx3=-3.4e38f;

    const ushort_t* mp = m_s + (size_t)rp0*64 + c4;

#define ACC4(U) { \
      float v0=bf2f_lo((U).x), v1=bf2f_hi((U).x), v2=bf2f_lo((U).y), v3=bf2f_hi((U).y); \
      sm0+=v0; sq0+=v0*v0; mn0=fminf(mn0,v0); mx0=fmaxf(mx0,v0); \
      sm1+=v1; sq1+=v1*v1; mn1=fminf(mn1,v1); mx1=fmaxf(mx1,v1); \
      sm2+=v2; sq2+=v2*v2; mn2=fminf(mn2,v2); mx2=fmaxf(mx2,v2); \
      sm3+=v3; sq3+=v3*v3; mn3=fminf(mn3,v3); mx3=fmaxf(mx3,v3); }

    int i = 0;
    for (; i + 2 <= deg; i += 2){
      uint2 ua = *reinterpret_cast<const uint2*>(mp + (size_t)i*64);
      uint2 ub = *reinterpret_cast<const uint2*>(mp + (size_t)(i+1)*64);
      ACC4(ua); ACC4(ub);
    }
    if (i < deg){
      uint2 ua = *reinterpret_cast<const uint2*>(mp + (size_t)i*64);
      ACC4(ua);
    }
#undef ACC4

    float invc = 1.f / (float)(deg>0?deg:1);
    float me0=sm0*invc, me1=sm1*invc, me2=sm2*invc, me3=sm3*invc;
    float sd0=__fsqrt_rn(fmaxf(sq0*invc-me0*me0,0.f)+1e-5f);
    float sd1=__fsqrt_rn(fmaxf(sq1*invc-me1*me1,0.f)+1e-5f);
    float sd2=__fsqrt_rn(fmaxf(sq2*invc-me2*me2,0.f)+1e-5f);
    float sd3=__fsqrt_rn(fmaxf(sq3*invc-me3*me3,0.f)+1e-5f);
    if (deg<=0){ mn0=mn1=mn2=mn3=0.f; mx0=mx1=mx2=mx3=0.f; }

    auto stw = [&](int s, short4_t val){
      int k0 = s*64 + c4;
      int ks = k0>>5, g2=(k0>>3)&3, j0 = c4&7;
      *reinterpret_cast<short4_t*>(&xl[(((wv*10+ks)*64 + g2*16 + q)<<3) + j0]) = val;
    };
    stw(0, (short4_t){(short)f2bf(sd0),(short)f2bf(sd1),(short)f2bf(sd2),(short)f2bf(sd3)});
    stw(1, (short4_t){(short)f2bf(mn0),(short)f2bf(mn1),(short)f2bf(mn2),(short)f2bf(mn3)});
    stw(2, (short4_t){(short)f2bf(mx0),(short)f2bf(mx1),(short)f2bf(mx2),(short)f2bf(mx3)});
    stw(3, (short4_t){(short)f2bf(me0),(short)f2bf(me1),(short)f2bf(me2),(short)f2bf(me3)});
    uint2 hu = {0u,0u};
    if (nv) hu = *reinterpret_cast<const uint2*>(hin + (size_t)n*64 + c4);
    stw(4, (short4_t){(short)(hu.x&0xffffu),(short)(hu.x>>16),(short)(hu.y&0xffffu),(short)(hu.y>>16)});
  }
  __syncthreads();

  int r0 = (lane>>4)*4;
  const short8* xw = reinterpret_cast<const short8*>(xl) + wv*10*64 + lane;
  const short8* w1 = reinterpret_cast<const short8*>(w1f) + lane;
  floatx4 acc[4];
  #pragma unroll
  for (int ct=0;ct<4;ct++){ float bb=b1[ct*16+(lane&15)]; acc[ct]=(floatx4){bb,bb,bb,bb}; }
  #pragma unroll
  for (int ks=0; ks<10; ks++){
    short8 a = xw[ks*64];
    #pragma unroll
    for (int ct=0;ct<4;ct++)
      acc[ct] = __builtin_amdgcn_mfma_f32_16x16x32_bf16(a, w1[(ks*4+ct)*64], acc[ct], 0,0,0);
  }
  __syncthreads();
  #pragma unroll
  for (int ct=0; ct<4; ct++){
    int colk = ct*16 + (lane&15);
    int ks2 = colk>>5, g2=(colk>>3)&3, j2=colk&7;
    #pragma unroll
    for (int j=0;j<4;j++)
      xl[(((wv*10+ks2)*64 + g2*16 + (r0+j))<<3) + j2] = (short)f2bf(fmaxf(acc[ct][j],0.f));
  }
  __syncthreads();

  const short8* w2 = reinterpret_cast<const short8*>(w2f) + lane;
  floatx4 mac[4];
  #pragma unroll
  for (int ct=0;ct<4;ct++){ float bb=b2[ct*16+(lane&15)]; mac[ct]=(floatx4){bb,bb,bb,bb}; }
  #pragma unroll
  for (int ks=0; ks<2; ks++){
    short8 a = xw[ks*64];
    #pragma unroll
    for (int ct=0;ct<4;ct++)
      mac[ct] = __builtin_amdgcn_mfma_f32_16x16x32_bf16(a, w2[(ks*4+ct)*64], mac[ct], 0,0,0);
  }
  #pragma unroll
  for (int ct=0;ct<4;ct++){
    int col = ct*16+(lane&15);
    #pragma unroll
    for (int j=0;j<4;j++){
      int n = n0 + wv*16 + r0 + j;
      if (n < NN){
        float v = mac[ct][j];
        emb[(size_t)n*64+col] = f2bf(v);
        hout[(size_t)n*64+col] = f2bf(fmaxf(v,0.f));
      }
    }
  }
}

// ------------------------- readout kernel (2-deep pipeline, float4 out) -----
// TPW_R=8: lighter prologue than k_edge -> finer grid doubles wave parallelism
// for this latency-bound kernel (HBM 12%, VALU 13%).
__launch_bounds__(256)
__global__ void k_readout(const ushort_t* __restrict__ emb,
                          const int* __restrict__ srcI, const int* __restrict__ dstI,
                          const float* __restrict__ ef,
                          const ushort_t* __restrict__ w1f,
                          const float* __restrict__ b1,
                          const float* __restrict__ w2, const float* __restrict__ b2,
                          float* __restrict__ out){
  int tid = threadIdx.x;
  int wv = tid>>6, lane = tid&63;
  int lo = lane&15, g = lane>>4;
  int wave = blockIdx.x*4 + wv;
  int t0 = wave*TPW_R;
  if (t0 >= NTILES) return;
  int t1 = t0 + TPW_R; if (t1 > NTILES) t1 = NTILES;

  const short8* w1 = reinterpret_cast<const short8*>(w1f) + lane;
  float bia[4];
  #pragma unroll
  for (int ct=0;ct<4;ct++) bia[ct] = b1[ct*16+lo];
  float w2v[4];
  #pragma unroll
  for (int ct=0;ct<4;ct++) w2v[ct] = w2[ct*16+lo];
  float bb2 = b2[0];
  int r0 = g*4;

  // prologue: indices+gathers for t0, indices for t0+1
  int pA = t0*16 + lo;
  int svA = srcI[pA], dvA = dstI[pA];
  float2 fA = reinterpret_cast<const float2*>(ef)[pA];
  short8 v0_ = *reinterpret_cast<const short8*>(emb + (size_t)svA*64 + g*8);
  short8 v1_ = *reinterpret_cast<const short8*>(emb + (size_t)svA*64 + (4+g)*8);
  short8 v2_ = *reinterpret_cast<const short8*>(emb + (size_t)dvA*64 + g*8);
  short8 v3_ = *reinterpret_cast<const short8*>(emb + (size_t)dvA*64 + (4+g)*8);
  int tB = (t0+1 < t1)? t0+1 : t0;
  int pB = tB*16 + lo;
  int svB = srcI[pB], dvB = dstI[pB];
  float2 fB = reinterpret_cast<const float2*>(ef)[pB];

  for (int t = t0; t < t1; ++t){
    // issue gathers for t+1 at top (full-body latency cover)
    short8 n0 = *reinterpret_cast<const short8*>(emb + (size_t)svB*64 + g*8);
    short8 n1 = *reinterpret_cast<const short8*>(emb + (size_t)svB*64 + (4+g)*8);
    short8 n2 = *reinterpret_cast<const short8*>(emb + (size_t)dvB*64 + g*8);
    short8 n3 = *reinterpret_cast<const short8*>(emb + (size_t)dvB*64 + (4+g)*8);
    int tC = (t+2 < t1)? t+2 : ((t+1 < t1)? t+1 : t);
    int pC = tC*16 + lo;
    int svC = srcI[pC], dvC = dstI[pC];
    float2 fC = reinterpret_cast<const float2*>(ef)[pC];

    unsigned evc = (unsigned)f2bf(fA.x) | ((unsigned)f2bf(fA.y)<<16);
    short8 b4v = {0,0,0,0,0,0,0,0};
    if (g==0){ b4v[0] = (short)(evc & 0xffffu); b4v[1] = (short)(evc >> 16); }

    floatx4 acc[4];
    #pragma unroll
    for (int ct=0;ct<4;ct++) acc[ct]=(floatx4){bia[ct],bia[ct],bia[ct],bia[ct]};
    __builtin_amdgcn_s_setprio(1);
    #pragma unroll
    for (int ct=0;ct<4;ct++) acc[ct] = __builtin_amdgcn_mfma_f32_16x16x32_bf16(v0_, w1[(0*4+ct)*64], acc[ct],0,0,0);
    #pragma unroll
    for (int ct=0;ct<4;ct++) acc[ct] = __builtin_amdgcn_mfma_f32_16x16x32_bf16(v1_, w1[(1*4+ct)*64], acc[ct],0,0,0);
    #pragma unroll
    for (int ct=0;ct<4;ct++) acc[ct] = __builtin_amdgcn_mfma_f32_16x16x32_bf16(v2_, w1[(2*4+ct)*64], acc[ct],0,0,0);
    #pragma unroll
    for (int ct=0;ct<4;ct++) acc[ct] = __builtin_amdgcn_mfma_f32_16x16x32_bf16(v3_, w1[(3*4+ct)*64], acc[ct],0,0,0);
    #pragma unroll
    for (int ct=0;ct<4;ct++) acc[ct] = __builtin_amdgcn_mfma_f32_16x16x32_bf16(b4v, w1[(4*4+ct)*64], acc[ct],0,0,0);
    __builtin_amdgcn_s_setprio(0);

    float part[4];
    #pragma unroll
    for (int j=0;j<4;j++){
      float pj = 0.f;
      #pragma unroll
      for (int ct=0;ct<4;ct++) pj += fmaxf(acc[ct][j],0.f)*w2v[ct];
      part[j] = pj;
    }
    #pragma unroll
    for (int m=1;m<16;m<<=1){
      #pragma unroll
      for (int j=0;j<4;j++) part[j] += __shfl_xor(part[j], m, 64);
    }
    if (lo==0){
      float4 o = make_float4(part[0]+bb2, part[1]+bb2, part[2]+bb2, part[3]+bb2);
      *reinterpret_cast<float4*>(out + t*16 + r0) = o;
    }

    v0_=n0; v1_=n1; v2_=n2; v3_=n3;
    fA = fB; fB = fC;
    svB = svC; dvB = dvC;
  }
}

// ------------------------- launcher -------------------------
extern "C" void kernel_launch(void* const* d_in, const int* in_sizes, int n_in,
                              void* d_out, int out_size, void* d_ws, size_t ws_size,
                              hipStream_t stream){
  const float* nf    = (const float*)d_in[0];
  const float* ef    = (const float*)d_in[1];
  const float* initW = (const float*)d_in[2];
  const float* initb = (const float*)d_in[3];
  const float* msgW1 = (const float*)d_in[4];
  const float* msgb1 = (const float*)d_in[5];
  const float* msgW2 = (const float*)d_in[6];
  const float* msgb2 = (const float*)d_in[7];
  const float* updW1 = (const float*)d_in[8];
  const float* updb1 = (const float*)d_in[9];
  const float* updW2 = (const float*)d_in[10];
  const float* updb2 = (const float*)d_in[11];
  const float* roW1  = (const float*)d_in[12];
  const float* rob1  = (const float*)d_in[13];
  const float* roW2  = (const float*)d_in[14];
  const float* rob2  = (const float*)d_in[15];
  const int*   eidx  = (const int*)d_in[16];
  const int* srcI = eidx;
  const int* dstI = eidx + NE;
  float* out = (float*)d_out;

  char* base = (char*)d_ws; size_t off = 0;
  auto alloc = [&](size_t b)->char*{ char* p = base + off; off = (off + b + 255) & ~(size_t)255; return p; };
  int* cnt    = (int*)alloc((size_t)NN*4);
  int* fill   = (int*)alloc((size_t)NN*4);
  int* rowptr = (int*)alloc((size_t)(NN+1)*4);
  int* bsum   = (int*)alloc(512*4);
  int* bfill  = (int*)alloc((size_t)NBUK*4);
  int4* btmp  = (int4*)alloc((size_t)NE*16);
  int2* edges = (int2*)alloc((size_t)NE*8);
  int* dsts   = (int*)alloc((size_t)NE*4);
  ushort_t* hA  = (ushort_t*)alloc((size_t)NN*64*2);
  ushort_t* hB  = (ushort_t*)alloc((size_t)NN*64*2);
  ushort_t* emb = (ushort_t*)alloc((size_t)NN*64*2);
  ushort_t* m_s = (ushort_t*)alloc((size_t)NE*64*2);
  ushort_t* msgW1f = (ushort_t*)alloc(5*2048*2);
  ushort_t* msgW2f = (ushort_t*)alloc(2*2048*2);
  ushort_t* updW1f = (ushort_t*)alloc(10*2048*2);
  ushort_t* updW2f = (ushort_t*)alloc(2*2048*2);
  ushort_t* roW1f  = (ushort_t*)alloc(5*2048*2);
  (void)ws_size; (void)in_sizes; (void)n_in; (void)out_size;

  hipMemsetAsync(cnt, 0, (size_t)NN*4, stream);
  int nb = (NN+255)/256;
  k_count<<<(NE/4+255)/256,256,0,stream>>>(dstI,cnt);
  k_scan1<<<nb,256,0,stream>>>(cnt,bsum);
  k_scan2<<<1,512,0,stream>>>(bsum,nb);
  k_scan3<<<nb,256,0,stream>>>(cnt,bsum,rowptr);
  hipMemcpyAsync(fill, rowptr, (size_t)NN*4, hipMemcpyDeviceToDevice, stream);
  k_filldst<<<nb,256,0,stream>>>(rowptr,dsts);
  k_binit<<<(NBUK+255)/256,256,0,stream>>>(rowptr,bfill);
  k_bin<<<NBLK_BIN,256,0,stream>>>(srcI,dstI,ef,bfill,btmp);
  k_sort2<<<NBUK,256,0,stream>>>(btmp,rowptr,fill,edges);
  k_wprep<<<(5*2048+255)/256,256,0,stream>>>(msgW1,msgW1f,130,5*2048);
  k_wprep<<<(2*2048+255)/256,256,0,stream>>>(msgW2,msgW2f,64,2*2048);
  k_wprep<<<(10*2048+255)/256,256,0,stream>>>(updW1,updW1f,320,10*2048);
  k_wprep<<<(2*2048+255)/256,256,0,stream>>>(updW2,updW2f,64,2*2048);
  k_wprep<<<(5*2048+255)/256,256,0,stream>>>(roW1,roW1f,130,5*2048);
  k_init<<<(NN*64+255)/256,256,0,stream>>>(nf,initW,initb,hA,emb);

  for (int it=0; it<ITERS; it++){
    const ushort_t* hin = (it&1)? hB : hA;
    ushort_t* hout      = (it&1)? hA : hB;
    k_edge<<<NBLK_E,256,0,stream>>>(hin,edges,dsts,msgW1f,msgW2f,msgb1,msgb2,m_s);
    k_update<<<NBLK_U,256,0,stream>>>(m_s,rowptr,hin,updW1f,updW2f,updb1,updb2,emb,hout);
  }
  k_readout<<<NBLK_R,256,0,stream>>>(emb,srcI,dstI,ef,roW1f,rob1,roW2,rob2,out);
}